// Round 5
// baseline (482.042 us; speedup 1.0000x reference)
//
#include <hip/hip_runtime.h>
#include <hip/hip_bf16.h>

typedef __hip_bfloat16 bf16;
typedef __attribute__((ext_vector_type(8))) short short8;
typedef __attribute__((ext_vector_type(4))) float floatx4;

#define NVP 10242
#define NV  40962
#define NF  81920
#define VPB 16

__device__ __forceinline__ float bfbits2f(unsigned short u) {
    union { unsigned int i; float f; } cv; cv.i = ((unsigned int)u) << 16;
    return cv.f;
}
__device__ __forceinline__ unsigned short f2bfbits(float f) {
    bf16 h = __float2bfloat16(f);
    return __builtin_bit_cast(unsigned short, h);
}
// fp8 e4m3 (OCP on gfx950). byte0 = fp8(a), byte1 = fp8(b).
__device__ __forceinline__ unsigned short pk_fp8(float a, float b) {
    int p = __builtin_amdgcn_cvt_pk_fp8_f32(a, b, 0, false);
    return (unsigned short)(p & 0xffff);
}
__device__ __forceinline__ float fp8_lo(unsigned int u) {
    return __builtin_amdgcn_cvt_f32_fp8(u, 0);
}
__device__ __forceinline__ float fp8_hi(unsigned int u) {
    return __builtin_amdgcn_cvt_f32_fp8(u, 1);
}

// ---------------------------------------------------------------------------
// K0: coeffs [o][c][k] -> coeffsB bf16 in MFMA 16x16x32 B-fragment layout:
//   coeffsB[((ot*8+kk)*64 + lane)*8 + j] = coeffs[o=ot*16+(lane&15)]
//                                                 [kg = kk*32+(lane>>4)*8+j]
// ---------------------------------------------------------------------------
__global__ void k_coeffsB(const float* __restrict__ coeffs,
                          unsigned short* __restrict__ coeffsB) {
    int t = blockIdx.x * 256 + threadIdx.x;       // 0..16383
    int j = t & 7, lane = (t >> 3) & 63, s = t >> 9;   // s = ot*8+kk
    int ot = s >> 3, kk = s & 7;
    int o  = ot * 16 + (lane & 15);
    int kg = kk * 32 + (lane >> 4) * 8 + j;
    coeffsB[t] = f2bfbits(coeffs[o * 256 + kg]);
}

// ---------------------------------------------------------------------------
// K1: per-b transpose + pad: x[c][v] fp32 -> xin[v][c] bf16 bits
// ---------------------------------------------------------------------------
__global__ void k_transpose(const float* __restrict__ x,
                            unsigned short* __restrict__ xin) {
    x   += (size_t)blockIdx.y * 64 * NVP;
    xin += (size_t)blockIdx.y * 64 * NV;
    __shared__ float tile[64][65];
    int v0 = blockIdx.x * 64;
    int tx = threadIdx.x & 63;
    int ty = threadIdx.x >> 6;
    int v  = v0 + tx;
#pragma unroll
    for (int r = 0; r < 16; ++r) {
        int c = ty + r * 4;
        tile[tx][c] = (v < NVP) ? x[c * NVP + v] : 1.0f;
    }
    __syncthreads();
#pragma unroll
    for (int r = 0; r < 16; ++r) {
        int vl = ty + r * 4;
        int vv = v0 + vl;
        if (vv < NV) xin[vv * 64 + tx] = f2bfbits(tile[vl][tx]);
    }
}

// ---------------------------------------------------------------------------
// K2: face gradients. 1D grid, b = blockIdx.x & (nb-1)  (XCD-pinned at nb=8:
// round-robin block->XCD dispatch puts all of batch b on XCD b, so each L2
// caches only one xin copy, 5.25 MB).
// One wave per face, lane = channel; indices scalarized -> s_loads.
// Output gfi: fp8 e4m3, [f][c][{ew,ns}] -> 128 B/face, one line.
// ---------------------------------------------------------------------------
__global__ void __launch_bounds__(256) k_facegrad(
    const unsigned short* __restrict__ xin,
    const int*   __restrict__ G_cols, const float* __restrict__ G_vals,
    const float* __restrict__ EW,     const float* __restrict__ NS,
    unsigned short* __restrict__ gfi, int nbm1) {
    int b  = blockIdx.x & nbm1;
    xin += (size_t)b * 64 * NV;
    gfi += (size_t)b * 64 * NF;
    int f  = ((blockIdx.x >> __popc(nbm1)) << 2) + (threadIdx.x >> 6);
    int fs = __builtin_amdgcn_readfirstlane(f);
    int c  = threadIdx.x & 63;
    float g[3];
#pragma unroll
    for (int d = 0; d < 3; ++d) {
        int base = (d * NF + fs) * 3;
        float acc = 0.f;
#pragma unroll
        for (int j = 0; j < 3; ++j) {
            int   col = G_cols[base + j];                // s_load (uniform)
            float val = G_vals[base + j];                // s_load
            acc += val * bfbits2f(xin[col * 64 + c]);
        }
        g[d] = acc;
    }
    float ew = g[0]*EW[fs*3+0] + g[1]*EW[fs*3+1] + g[2]*EW[fs*3+2];
    float ns = g[0]*NS[fs*3+0] + g[1]*NS[fs*3+1] + g[2]*NS[fs*3+2];
    gfi[fs * 64 + c] = pk_fp8(ew, ns);                   // 128 B/wave store
}

// ---------------------------------------------------------------------------
// K3: vertex kernel. 1D grid, b = blockIdx.x & (nb-1) (XCD-pinned at nb=8).
// Block 256 (4 waves), 16 vertices.
// Phase 1 (lane=c): scalarized gathers; gf gathers are single-line fp8 pairs.
// Phase 2: wave w -> o-tile w via 8x mfma_f32_16x16x32_bf16.
// Epilogue: f32 transpose LDS -> coalesced out[o][v] store.
// ---------------------------------------------------------------------------
__global__ void __launch_bounds__(256) k_vertex(
    const unsigned short* __restrict__ xin,
    const int*  __restrict__ L_cols,   const float* __restrict__ L_vals,
    const int*  __restrict__ F2V_cols, const float* __restrict__ F2V_vals,
    const unsigned short* __restrict__ gfi,
    const unsigned short* __restrict__ coeffsB,
    const float* __restrict__ bias,
    float* __restrict__ out, int nbm1) {
    int b = blockIdx.x & nbm1;
    xin += (size_t)b * 64 * NV;
    gfi += (size_t)b * 64 * NF;
    out += (size_t)b * 64 * NV;
    int vb = (blockIdx.x >> __popc(nbm1)) * VPB;

    __shared__ unsigned short feat[VPB * 264];   // 8448 B
    __shared__ float outs[VPB * 65];             // 4160 B
    int w    = threadIdx.x >> 6;
    int lane = threadIdx.x & 63;
    int c    = lane;

    // ---- phase 1: feat build, 4 vertices per wave, scalarized indices ----
#pragma unroll
    for (int i = 0; i < 4; ++i) {
        int vloc = w * 4 + i;
        int v    = vb + vloc;
        int vcs  = __builtin_amdgcn_readfirstlane(v < NV ? v : NV - 1);
        float f0 = bfbits2f(xin[vcs * 64 + c]);
        float lap = 0.f;
        int lb = vcs * 7;
#pragma unroll
        for (int j = 0; j < 7; ++j) {
            int   col = L_cols[lb + j];                  // s_load
            float val = L_vals[lb + j];                  // s_load
            lap += val * bfbits2f(xin[col * 64 + c]);
        }
        float ew = 0.f, ns = 0.f;
        int fb = vcs * 6;
#pragma unroll
        for (int j = 0; j < 6; ++j) {
            int   col = F2V_cols[fb + j];                // s_load
            float val = F2V_vals[fb + j];                // s_load
            unsigned int u = gfi[col * 64 + c];          // 1 line, both vals
            ew += val * fp8_lo(u);
            ns += val * fp8_hi(u);
        }
        ushort4 p = make_ushort4(f2bfbits(f0), f2bfbits(lap),
                                 f2bfbits(ew), f2bfbits(ns));
        *(ushort4*)&feat[vloc * 264 + c * 4] = p;        // 8B, 2-way (free)
    }
    __syncthreads();

    // ---- phase 2: MFMA, wave w -> o-tile w (o = w*16 .. w*16+15) ----
    int m = lane & 15, quad = lane >> 4;
    float bo = bias[w * 16 + m];
    floatx4 acc = {bo, bo, bo, bo};
#pragma unroll
    for (int kk = 0; kk < 8; ++kk) {
        short8 a = *(const short8*)&feat[m * 264 + kk * 32 + quad * 8];
        short8 bfr = *(const short8*)&coeffsB[((w * 8 + kk) * 64 + lane) * 8];
        acc = __builtin_amdgcn_mfma_f32_16x16x32_bf16(a, bfr, acc, 0, 0, 0);
    }

    // ---- epilogue: C layout col=lane&15 (o), row=quad*4+reg (v) ----
#pragma unroll
    for (int r = 0; r < 4; ++r)
        outs[(quad * 4 + r) * 65 + w * 16 + m] = acc[r];
    __syncthreads();
    int vp = threadIdx.x & 15;
    int og = threadIdx.x >> 4;
    if (vb + vp < NV) {
#pragma unroll
        for (int r = 0; r < 4; ++r) {
            int o2 = og + r * 16;
            out[(size_t)o2 * NV + vb + vp] = outs[vp * 65 + o2];
        }
    }
}

// ---------------------------------------------------------------------------
extern "C" void kernel_launch(void* const* d_in, const int* in_sizes, int n_in,
                              void* d_out, int out_size, void* d_ws, size_t ws_size,
                              hipStream_t stream) {
    const float* x        = (const float*)d_in[0];
    const int*   G_cols   = (const int*)  d_in[2];
    const float* G_vals   = (const float*)d_in[3];
    const int*   L_cols   = (const int*)  d_in[5];
    const float* L_vals   = (const float*)d_in[6];
    const int*   F2V_cols = (const int*)  d_in[8];
    const float* F2V_vals = (const float*)d_in[9];
    const float* EW       = (const float*)d_in[10];
    const float* NS       = (const float*)d_in[11];
    const float* coeffs   = (const float*)d_in[12];
    const float* bias     = (const float*)d_in[13];
    float* out = (float*)d_out;

    char* ws = (char*)d_ws;
    const size_t xin_b = (size_t)NV * 64;   // ushorts per batch
    const size_t gf_b  = (size_t)NF * 64;   // ushorts per batch (fp8 pairs)
    // ws-adaptive batching (path fixed for a given ws_size -> graph-safe)
    size_t need8 = 65536 + (8 * xin_b + 8 * gf_b) * 2;   // ~126 MB
    size_t need2 = 65536 + (2 * xin_b + 2 * gf_b) * 2;   // ~31.6 MB
    int nb = (ws_size >= need8) ? 8 : (ws_size >= need2) ? 2 : 1;
    int nbm1 = nb - 1;

    unsigned short* coeffsB = (unsigned short*)ws;          // 32 KB
    unsigned short* xin = (unsigned short*)(ws + 65536);    // nb * 5.25 MB
    unsigned short* gfi = xin + (size_t)nb * xin_b;         // nb * 10.5 MB

    k_coeffsB<<<64, 256, 0, stream>>>(coeffs, coeffsB);
    for (int b0 = 0; b0 < 8; b0 += nb) {
        dim3 gt(641, nb);
        k_transpose<<<gt, 256, 0, stream>>>(x + (size_t)b0 * 64 * NVP, xin);
        k_facegrad<<<nb * (NF / 4), 256, 0, stream>>>(
            xin, G_cols, G_vals, EW, NS, gfi, nbm1);
        k_vertex<<<nb * ((NV + VPB - 1) / VPB), 256, 0, stream>>>(
            xin, L_cols, L_vals, F2V_cols, F2V_vals, gfi,
            coeffsB, bias, out + (size_t)b0 * 64 * NV, nbm1);
    }
}

// Round 6
// 454.667 us; speedup vs baseline: 1.0602x; 1.0602x over previous
//
#include <hip/hip_runtime.h>
#include <hip/hip_bf16.h>

typedef __hip_bfloat16 bf16;
typedef __attribute__((ext_vector_type(8))) short short8;
typedef __attribute__((ext_vector_type(4))) float floatx4;

#define NVP 10242
#define NV  40962
#define NF  81920
#define VPB 16

__device__ __forceinline__ float bfbits2f(unsigned short u) {
    union { unsigned int i; float f; } cv; cv.i = ((unsigned int)u) << 16;
    return cv.f;
}
__device__ __forceinline__ unsigned short f2bfbits(float f) {
    bf16 h = __float2bfloat16(f);
    return __builtin_bit_cast(unsigned short, h);
}
// fp8 e4m3 (OCP on gfx950)
__device__ __forceinline__ unsigned short pk_fp8(float a, float b) {
    int p = __builtin_amdgcn_cvt_pk_fp8_f32(a, b, 0, false);
    return (unsigned short)(p & 0xffff);
}
__device__ __forceinline__ unsigned char one_fp8(float a) {
    int p = __builtin_amdgcn_cvt_pk_fp8_f32(a, 0.f, 0, false);
    return (unsigned char)(p & 0xff);
}
__device__ __forceinline__ float fp8_lo(unsigned int u) {
    return __builtin_amdgcn_cvt_f32_fp8(u, 0);
}
__device__ __forceinline__ float fp8_hi(unsigned int u) {
    return __builtin_amdgcn_cvt_f32_fp8(u, 1);
}

// ---------------------------------------------------------------------------
// K0: coeffs [o][c][k] -> coeffsB bf16 in MFMA 16x16x32 B-fragment layout
// ---------------------------------------------------------------------------
__global__ void k_coeffsB(const float* __restrict__ coeffs,
                          unsigned short* __restrict__ coeffsB) {
    int t = blockIdx.x * 256 + threadIdx.x;       // 0..16383
    int j = t & 7, lane = (t >> 3) & 63, s = t >> 9;   // s = ot*8+kk
    int ot = s >> 3, kk = s & 7;
    int o  = ot * 16 + (lane & 15);
    int kg = kk * 32 + (lane >> 4) * 8 + j;
    coeffsB[t] = f2bfbits(coeffs[o * 256 + kg]);
}

// ---------------------------------------------------------------------------
// K1: per-b transpose + pad: x[c][v] fp32 -> xin[v][c] bf16 + xin8[v][c] fp8.
// xin8 (2.6 MB/batch) fits one XCD L2 -> facegrad gathers become L2 hits.
// ---------------------------------------------------------------------------
__global__ void k_transpose(const float* __restrict__ x,
                            unsigned short* __restrict__ xin,
                            unsigned char* __restrict__ xin8) {
    x    += (size_t)blockIdx.y * 64 * NVP;
    xin  += (size_t)blockIdx.y * 64 * NV;
    xin8 += (size_t)blockIdx.y * 64 * NV;
    __shared__ float tile[64][65];
    int v0 = blockIdx.x * 64;
    int tx = threadIdx.x & 63;
    int ty = threadIdx.x >> 6;
    int v  = v0 + tx;
#pragma unroll
    for (int r = 0; r < 16; ++r) {
        int c = ty + r * 4;
        tile[tx][c] = (v < NVP) ? x[c * NVP + v] : 1.0f;
    }
    __syncthreads();
#pragma unroll
    for (int r = 0; r < 16; ++r) {
        int vl = ty + r * 4;
        int vv = v0 + vl;
        if (vv < NV) {
            float val = tile[vl][tx];
            xin [vv * 64 + tx] = f2bfbits(val);
            xin8[vv * 64 + tx] = one_fp8(val);
        }
    }
}

// ---------------------------------------------------------------------------
// K2: face gradients. 2D grid (y = batch; batch-sequential dispatch -> xin8
// replicated in all XCD L2s). One wave per face, lane = channel; indices
// scalarized -> s_loads. Gathers read fp8 xin8 (64 B/wave, L2-resident).
// Output gfi: fp8 pair [f][c][{ew,ns}], 128 B/face.
// ---------------------------------------------------------------------------
__global__ void __launch_bounds__(256) k_facegrad(
    const unsigned char* __restrict__ xin8,
    const int*   __restrict__ G_cols, const float* __restrict__ G_vals,
    const float* __restrict__ EW,     const float* __restrict__ NS,
    unsigned short* __restrict__ gfi) {
    xin8 += (size_t)blockIdx.y * 64 * NV;
    gfi  += (size_t)blockIdx.y * 64 * NF;
    int f  = (blockIdx.x << 2) + (threadIdx.x >> 6);
    int fs = __builtin_amdgcn_readfirstlane(f);
    int c  = threadIdx.x & 63;
    float g[3];
#pragma unroll
    for (int d = 0; d < 3; ++d) {
        int base = (d * NF + fs) * 3;
        float acc = 0.f;
#pragma unroll
        for (int j = 0; j < 3; ++j) {
            int   col = G_cols[base + j];                // s_load (uniform)
            float val = G_vals[base + j];                // s_load
            acc += val * fp8_lo((unsigned int)xin8[col * 64 + c]);
        }
        g[d] = acc;
    }
    float ew = g[0]*EW[fs*3+0] + g[1]*EW[fs*3+1] + g[2]*EW[fs*3+2];
    float ns = g[0]*NS[fs*3+0] + g[1]*NS[fs*3+1] + g[2]*NS[fs*3+2];
    gfi[fs * 64 + c] = pk_fp8(ew, ns);                   // 128 B/wave store
}

// ---------------------------------------------------------------------------
// K3: vertex kernel. 2D grid (y = batch). Block 256 (4 waves), 16 vertices.
// Phase 1 (lane=c): scalarized gathers (bf16 xin, fp8-pair gfi).
// Phase 2: wave w -> o-tile w via 8x mfma_f32_16x16x32_bf16.
// Epilogue: f32 transpose LDS -> coalesced out[o][v] store.
// ---------------------------------------------------------------------------
__global__ void __launch_bounds__(256) k_vertex(
    const unsigned short* __restrict__ xin,
    const int*  __restrict__ L_cols,   const float* __restrict__ L_vals,
    const int*  __restrict__ F2V_cols, const float* __restrict__ F2V_vals,
    const unsigned short* __restrict__ gfi,
    const unsigned short* __restrict__ coeffsB,
    const float* __restrict__ bias,
    float* __restrict__ out) {
    xin += (size_t)blockIdx.y * 64 * NV;
    gfi += (size_t)blockIdx.y * 64 * NF;
    out += (size_t)blockIdx.y * 64 * NV;
    int vb = blockIdx.x * VPB;

    __shared__ unsigned short feat[VPB * 264];   // 8448 B
    __shared__ float outs[VPB * 65];             // 4160 B
    int w    = threadIdx.x >> 6;
    int lane = threadIdx.x & 63;
    int c    = lane;

    // ---- phase 1: feat build, 4 vertices per wave, scalarized indices ----
#pragma unroll
    for (int i = 0; i < 4; ++i) {
        int vloc = w * 4 + i;
        int v    = vb + vloc;
        int vcs  = __builtin_amdgcn_readfirstlane(v < NV ? v : NV - 1);
        float f0 = bfbits2f(xin[vcs * 64 + c]);
        float lap = 0.f;
        int lb = vcs * 7;
#pragma unroll
        for (int j = 0; j < 7; ++j) {
            int   col = L_cols[lb + j];                  // s_load
            float val = L_vals[lb + j];                  // s_load
            lap += val * bfbits2f(xin[col * 64 + c]);
        }
        float ew = 0.f, ns = 0.f;
        int fb = vcs * 6;
#pragma unroll
        for (int j = 0; j < 6; ++j) {
            int   col = F2V_cols[fb + j];                // s_load
            float val = F2V_vals[fb + j];                // s_load
            unsigned int u = gfi[col * 64 + c];          // 1 line, both vals
            ew += val * fp8_lo(u);
            ns += val * fp8_hi(u);
        }
        ushort4 p = make_ushort4(f2bfbits(f0), f2bfbits(lap),
                                 f2bfbits(ew), f2bfbits(ns));
        *(ushort4*)&feat[vloc * 264 + c * 4] = p;        // 8B, 2-way (free)
    }
    __syncthreads();

    // ---- phase 2: MFMA, wave w -> o-tile w (o = w*16 .. w*16+15) ----
    int m = lane & 15, quad = lane >> 4;
    float bo = bias[w * 16 + m];
    floatx4 acc = {bo, bo, bo, bo};
#pragma unroll
    for (int kk = 0; kk < 8; ++kk) {
        short8 a = *(const short8*)&feat[m * 264 + kk * 32 + quad * 8];
        short8 bfr = *(const short8*)&coeffsB[((w * 8 + kk) * 64 + lane) * 8];
        acc = __builtin_amdgcn_mfma_f32_16x16x32_bf16(a, bfr, acc, 0, 0, 0);
    }

    // ---- epilogue: C layout col=lane&15 (o), row=quad*4+reg (v) ----
#pragma unroll
    for (int r = 0; r < 4; ++r)
        outs[(quad * 4 + r) * 65 + w * 16 + m] = acc[r];
    __syncthreads();
    int vp = threadIdx.x & 15;
    int og = threadIdx.x >> 4;
    if (vb + vp < NV) {
#pragma unroll
        for (int r = 0; r < 4; ++r) {
            int o2 = og + r * 16;
            out[(size_t)o2 * NV + vb + vp] = outs[vp * 65 + o2];
        }
    }
}

// ---------------------------------------------------------------------------
extern "C" void kernel_launch(void* const* d_in, const int* in_sizes, int n_in,
                              void* d_out, int out_size, void* d_ws, size_t ws_size,
                              hipStream_t stream) {
    const float* x        = (const float*)d_in[0];
    const int*   G_cols   = (const int*)  d_in[2];
    const float* G_vals   = (const float*)d_in[3];
    const int*   L_cols   = (const int*)  d_in[5];
    const float* L_vals   = (const float*)d_in[6];
    const int*   F2V_cols = (const int*)  d_in[8];
    const float* F2V_vals = (const float*)d_in[9];
    const float* EW       = (const float*)d_in[10];
    const float* NS       = (const float*)d_in[11];
    const float* coeffs   = (const float*)d_in[12];
    const float* bias     = (const float*)d_in[13];
    float* out = (float*)d_out;

    char* ws = (char*)d_ws;
    const size_t xin_b = (size_t)NV * 64;   // elements per batch
    const size_t gf_b  = (size_t)NF * 64;
    // per-batch bytes: xin bf16 2*xin_b + gfi 2*gf_b + xin8 1*xin_b
    size_t perb = 2 * xin_b + 2 * gf_b + xin_b;
    size_t need8 = 65536 + 8 * perb;    // ~147 MB
    size_t need2 = 65536 + 2 * perb;    // ~37 MB
    int nb = (ws_size >= need8) ? 8 : (ws_size >= need2) ? 2 : 1;

    unsigned short* coeffsB = (unsigned short*)ws;            // 32 KB
    unsigned short* xin  = (unsigned short*)(ws + 65536);     // nb*5.25 MB
    unsigned short* gfi  = xin + (size_t)nb * xin_b;          // nb*10.5 MB
    unsigned char*  xin8 = (unsigned char*)(gfi + (size_t)nb * gf_b); // nb*2.6MB

    k_coeffsB<<<64, 256, 0, stream>>>(coeffs, coeffsB);
    for (int b0 = 0; b0 < 8; b0 += nb) {
        dim3 gt(641, nb), gg(NF / 4, nb), gv((NV + VPB - 1) / VPB, nb);
        k_transpose<<<gt, 256, 0, stream>>>(x + (size_t)b0 * 64 * NVP, xin, xin8);
        k_facegrad<<<gg, 256, 0, stream>>>(xin8, G_cols, G_vals, EW, NS, gfi);
        k_vertex<<<gv, 256, 0, stream>>>(xin, L_cols, L_vals, F2V_cols, F2V_vals,
                                         gfi, coeffsB, bias,
                                         out + (size_t)b0 * 64 * NV);
    }
}